// Round 17
// baseline (712.805 us; speedup 1.0000x reference)
//
#include <hip/hip_runtime.h>

typedef unsigned short u16;
typedef __bf16 bf16x8 __attribute__((ext_vector_type(8)));
typedef float f32x4 __attribute__((ext_vector_type(4)));

__device__ __forceinline__ float b2f(u16 u) { return __builtin_bit_cast(float, (unsigned)u << 16); }
__device__ __forceinline__ u16 f2b(float f) {
  unsigned x = __builtin_bit_cast(unsigned, f);
  x += 0x7fffu + ((x >> 16) & 1u);
  return (u16)(x >> 16);
}

__device__ __forceinline__ void gload16(const u16* g, u16* l) {
  auto gp = (__attribute__((address_space(1))) void*)(void*)const_cast<u16*>(g);
  auto lp = (__attribute__((address_space(3))) void*)(void*)l;
  __builtin_amdgcn_global_load_lds(gp, lp, 16, 0, 0);
}

__device__ __forceinline__ f32x4 mfma16(bf16x8 a, bf16x8 b, f32x4 c) {
  return __builtin_amdgcn_mfma_f32_16x16x32_bf16(a, b, c, 0, 0, 0);
}

// overflow-stable tanh-form GELU (hardware v_exp_f32)
__device__ __forceinline__ float gelu_fast(float v) {
  float u = v * (0.7978845608028654f + 0.03567740813636141f * v * v);
  float e = __expf(2.0f * u);
  float th = 1.0f - 2.0f / (e + 1.0f);
  return 0.5f * v * (1.0f + th);
}

// ---------------- ALL weight transposes + bkv assembly in ONE launch ----------------
// tiles: [0,2304) Wq/Wk/Wv/Wo; [2304,4608) W1; [4608,6912) W2; [6912] copies bk|bv -> bkv
__global__ __launch_bounds__(256) void transpose_all(const float* __restrict__ Wq, const float* __restrict__ Wk,
                                                     const float* __restrict__ Wv, const float* __restrict__ Wo,
                                                     const float* __restrict__ W1, const float* __restrict__ W2,
                                                     const float* __restrict__ bk, const float* __restrict__ bv,
                                                     u16* __restrict__ WqT, u16* __restrict__ WkvT,
                                                     u16* __restrict__ WoT, u16* __restrict__ W1T,
                                                     u16* __restrict__ W2T, float* __restrict__ bkv) {
  __shared__ float tile[32][33];
  const int t = blockIdx.x;
  if (t == 6912) {
    const int i = threadIdx.y * 32 + threadIdx.x;
    for (int c = i; c < 768; c += 256) {
      bkv[c] = bk[c];
      bkv[768 + c] = bv[c];
    }
    return;
  }
  const float* in;
  u16* out;
  int R, C, tx, ty;
  if (t < 2304) {
    const int z = t / 576, r = t % 576;
    tx = r % 24; ty = r / 24; R = 768; C = 768;
    in = (z == 0) ? Wq : (z == 1) ? Wk : (z == 2) ? Wv : Wo;
    out = (z == 0) ? WqT : (z == 1) ? WkvT : (z == 2) ? (WkvT + (size_t)768 * 768) : WoT;
  } else if (t < 4608) {
    const int r = t - 2304;
    tx = r % 96; ty = r / 96; R = 768; C = 3072;
    in = W1; out = W1T;
  } else {
    const int r = t - 4608;
    tx = r % 24; ty = r / 24; R = 3072; C = 768;
    in = W2; out = W2T;
  }
  const int bx = tx * 32, by = ty * 32;
  const int x = threadIdx.x;
  for (int yy = threadIdx.y; yy < 32; yy += 8) tile[yy][x] = in[(size_t)(by + yy) * C + bx + x];
  __syncthreads();
  for (int yy = threadIdx.y; yy < 32; yy += 8) out[(size_t)(bx + yy) * R + by + x] = f2b(tile[x][yy]);
}

// ---------------- BN on row 0, both modalities in one launch ----------------
__global__ __launch_bounds__(256) void bn_both(const float* __restrict__ imgf, const float* __restrict__ txtf,
                                               const float* gi, const float* bi, const float* mi, const float* vi,
                                               const float* gt, const float* bt, const float* mt, const float* vt,
                                               float* __restrict__ out) {
  const int bb = blockIdx.x, z = blockIdx.y;
  const float* row = z ? (txtf + (size_t)bb * 64 * 768) : (imgf + (size_t)bb * 197 * 768);
  const float *g = z ? gt : gi, *b = z ? bt : bi, *m = z ? mt : mi, *v = z ? vt : vi;
  float* o = out + (size_t)z * 98304 + bb * 768;
  for (int d = threadIdx.x; d < 768; d += 256) {
    float x = row[d];
    o[d] = (x - m[d]) * (1.0f / sqrtf(v[d] + 1e-5f)) * g[d] + b[d];
  }
}

// ---------------- stable top-k, both modalities in one launch ----------------
__global__ __launch_bounds__(256) void topk_both(const float* __restrict__ img_score,
                                                 const float* __restrict__ txt_score,
                                                 int* __restrict__ sel_i, int* __restrict__ sel_t) {
  __shared__ float s[256];
  const int b = blockIdx.x, z = blockIdx.y;
  const float* score = z ? txt_score : img_score;
  int* sel = z ? sel_t : sel_i;
  const int L = z ? 64 : 197, Ksel = z ? 19 : 59, Lq = z ? 20 : 60;
  const int stride2 = 128 * Lq;
  for (int i = threadIdx.x; i < L; i += 256) {
    float v = score[b * L + i];
    s[i] = (i == 0) ? 0.0f : v;
  }
  __syncthreads();
  for (int i = threadIdx.x; i < L; i += 256) {
    float si = s[i];
    int rank = 0;
    for (int j = 0; j < L; ++j) {
      float sj = s[j];
      rank += (sj > si) || (sj == si && j < i);
    }
    if (rank < Ksel) sel[b * Lq + rank + 1] = i;
    else if (rank < 2 * Ksel) sel[stride2 + b * Lq + (rank - Ksel) + 1] = i;
  }
  if (threadIdx.x == 0) { sel[b * Lq] = 0; sel[stride2 + b * Lq] = 0; }
}

// ---------------- LN1 over the combined 33408-row space ----------------
__global__ __launch_bounds__(256) void ln1_both(const float* __restrict__ imgf, const float* __restrict__ txtf,
                                                const float* g, const float* b, u16* __restrict__ out) {
  const int row = blockIdx.x * 4 + (threadIdx.x >> 6);
  const int l = threadIdx.x & 63;
  const float* xr = (row < 25216) ? (imgf + (size_t)row * 768) : (txtf + (size_t)(row - 25216) * 768);
  float v[12]; float s = 0.f;
#pragma unroll
  for (int i = 0; i < 12; ++i) { v[i] = xr[l + i * 64]; s += v[i]; }
  for (int d = 1; d < 64; d <<= 1) s += __shfl_xor(s, d);
  const float mu = s * (1.0f / 768.0f);
  float q = 0.f;
#pragma unroll
  for (int i = 0; i < 12; ++i) { float t = v[i] - mu; q += t * t; }
  for (int d = 1; d < 64; d <<= 1) q += __shfl_xor(q, d);
  const float rs = 1.0f / sqrtf(q * (1.0f / 768.0f) + 1e-5f);
#pragma unroll
  for (int i = 0; i < 12; ++i) {
    int c = l + i * 64;
    out[(size_t)row * 768 + c] = f2b((v[i] - mu) * rs * g[c] + b[c]);
  }
}

// ---------------- LayerNorm (f32 in -> bf16 out), one wave per 768-row ----------------
__global__ __launch_bounds__(256) void ln_rows(const float* __restrict__ x, const float* g, const float* b,
                                               u16* __restrict__ out) {
  const int row = blockIdx.x * 4 + (threadIdx.x >> 6);
  const int l = threadIdx.x & 63;
  const float* xr = x + (size_t)row * 768;
  float v[12]; float s = 0.f;
#pragma unroll
  for (int i = 0; i < 12; ++i) { v[i] = xr[l + i * 64]; s += v[i]; }
  for (int d = 1; d < 64; d <<= 1) s += __shfl_xor(s, d);
  const float mu = s * (1.0f / 768.0f);
  float q = 0.f;
#pragma unroll
  for (int i = 0; i < 12; ++i) { float t = v[i] - mu; q += t * t; }
  for (int d = 1; d < 64; d <<= 1) q += __shfl_xor(q, d);
  const float rs = 1.0f / sqrtf(q * (1.0f / 768.0f) + 1e-5f);
#pragma unroll
  for (int i = 0; i < 12; ++i) {
    int c = l + i * 64;
    out[(size_t)row * 768 + c] = f2b((v[i] - mu) * rs * g[c] + b[c]);
  }
}

// ---------------- both gathers in one launch ----------------
__global__ __launch_bounds__(128) void gather_both(const int* __restrict__ sel_i, const int* __restrict__ sel_t,
                                                   const u16* __restrict__ kn, const float* __restrict__ imgf,
                                                   const float* __restrict__ txtf, u16* __restrict__ qn,
                                                   float* __restrict__ xs) {
  const int bx = blockIdx.x, by = blockIdx.y;
  const int p = by >> 7, b = by & 127;
  const int* sel;
  const u16* knp;
  const float* feats;
  int Lq, Lsrc, q, rowbase;
  if (bx < 60) {
    sel = sel_i; knp = kn; feats = imgf; Lq = 60; Lsrc = 197; q = bx; rowbase = 0;
  } else {
    sel = sel_t; knp = kn + (size_t)25216 * 768; feats = txtf; Lq = 20; Lsrc = 64; q = bx - 60; rowbase = 15360;
  }
  const int prow = (p * 128 + b) * Lq + q;
  const int row = rowbase + prow;
  const int src = sel[prow];
  const uint4* sq = (const uint4*)(knp + ((size_t)b * Lsrc + src) * 768);
  uint4* dq = (uint4*)(qn + (size_t)row * 768);
  for (int c = threadIdx.x; c < 96; c += 128) dq[c] = sq[c];
  const float4* sx = (const float4*)(feats + ((size_t)b * Lsrc + src) * 768);
  float4* dx = (float4*)(xs + (size_t)row * 768);
  for (int c = threadIdx.x; c < 192; c += 128) dx[c] = sx[c];
}

enum { EPI_PLAIN = 0, EPI_QSCALE = 1, EPI_GELU = 2, EPI_RES_FADD = 3, EPI_RES_OUT = 4 };

template <int EPI>
__device__ __forceinline__ void epi_write(float v, size_t off, void* outp, const float* res) {
  if constexpr (EPI == EPI_QSCALE) {
    ((u16*)outp)[off] = f2b(v * 0.125f);
  } else if constexpr (EPI == EPI_GELU) {
    ((u16*)outp)[off] = f2b(gelu_fast(v));
  } else if constexpr (EPI == EPI_RES_FADD || EPI == EPI_RES_OUT) {
    ((float*)outp)[off] = v + res[off];
  } else {
    ((u16*)outp)[off] = f2b(v);
  }
}

// ---------------- GEMM 128^2, BK=32, 2-phase dbuf, 32KB LDS; bounds(256,4) [best known] ----------------
template <int EPI>
__global__ __launch_bounds__(256, 4) void gemm_bt(const u16* __restrict__ A, const u16* __restrict__ Bt,
                                                  const float* __restrict__ bias, const float* __restrict__ res,
                                                  void* __restrict__ outp, int M, int N, int K) {
  __shared__ alignas(16) u16 As[2][4096];
  __shared__ alignas(16) u16 Bs[2][4096];
  const int tid = threadIdx.x, l = tid & 63, w = tid >> 6;
  const int nwg = gridDim.x * gridDim.y;
  int lin = blockIdx.y * gridDim.x + blockIdx.x;
  const int q8 = nwg >> 3, r8 = nwg & 7;
  const int xcd = lin & 7, pos = lin >> 3;
  const int nl = (xcd < r8) ? (xcd * (q8 + 1) + pos) : (r8 * (q8 + 1) + (xcd - r8) * q8 + pos);
  const int m0 = (nl / gridDim.x) * 128, n0 = (nl % gridDim.x) * 128;
  const int wm = (w & 1) * 64, wn = (w >> 1) * 64;
  f32x4 acc[4][4] = {};

  int arow_g[2], ach_g[2];
#pragma unroll
  for (int p = 0; p < 2; ++p) {
    const int s = p * 256 + tid;
    const int rl = s >> 3, v = (s & 7) ^ (rl & 7);
    arow_g[p] = (v >> 2) * 64 + rl;
    ach_g[p] = (v & 3) * 8;
  }
  auto STAGE = [&](int buf, int k0) {
#pragma unroll
    for (int p = 0; p < 2; ++p) {
      const int s = p * 256 + tid;
      gload16(A + (size_t)(m0 + arow_g[p]) * K + k0 + ach_g[p], &As[buf][s * 8]);
      gload16(Bt + (size_t)(n0 + arow_g[p]) * K + k0 + ach_g[p], &Bs[buf][s * 8]);
    }
  };

  const int c = l >> 4;
  auto COMPUTE = [&](int buf) {
    bf16x8 af[4], bfr[4];
#pragma unroll
    for (int i = 0; i < 4; ++i) {
      const int arow = wm + i * 16 + (l & 15);
      const int slot = (c | ((arow >> 6) << 2)) ^ (arow & 7);
      af[i] = *(const bf16x8*)&As[buf][(arow & 63) * 64 + slot * 8];
      const int brow = wn + i * 16 + (l & 15);
      const int slotb = (c | ((brow >> 6) << 2)) ^ (brow & 7);
      bfr[i] = *(const bf16x8*)&Bs[buf][(brow & 63) * 64 + slotb * 8];
    }
    __builtin_amdgcn_s_setprio(1);
#pragma unroll
    for (int mi = 0; mi < 4; ++mi)
#pragma unroll
      for (int ni = 0; ni < 4; ++ni) acc[mi][ni] = mfma16(af[mi], bfr[ni], acc[mi][ni]);
    __builtin_amdgcn_s_setprio(0);
  };

  const int NT = K >> 5;
  STAGE(0, 0);
  int cur = 0;
  for (int t = 0; t < NT - 1; ++t) {
    STAGE(cur ^ 1, (t + 1) << 5);
    asm volatile("s_waitcnt vmcnt(4)" ::: "memory");
    __builtin_amdgcn_sched_barrier(0);
    __builtin_amdgcn_s_barrier();
    COMPUTE(cur);
    __builtin_amdgcn_s_barrier();
    cur ^= 1;
  }
  asm volatile("s_waitcnt vmcnt(0)" ::: "memory");
  __builtin_amdgcn_sched_barrier(0);
  __builtin_amdgcn_s_barrier();
  COMPUTE(cur);

  const int r4 = (l >> 4) * 4, c16 = l & 15;
#pragma unroll
  for (int mi = 0; mi < 4; ++mi)
#pragma unroll
    for (int ni = 0; ni < 4; ++ni) {
      const int gn = n0 + wn + ni * 16 + c16;
      const float bia = bias[gn];
#pragma unroll
      for (int j = 0; j < 4; ++j) {
        const int gm = m0 + wm + mi * 16 + r4 + j;
        epi_write<EPI>(acc[mi][ni][j] + bia, (size_t)gm * N + gn, outp, res);
      }
    }
}

// ---------------- attention body (dynamic-LDS), K/V interleaved [row][1536] ----------------
template <int LQP, int LKP, int LQ, int LK, bool MASK>
__device__ __forceinline__ void attn_body(char* smraw, const u16* __restrict__ Q, const u16* __restrict__ KVb,
                                          const int* __restrict__ toks, u16* __restrict__ O, int by, int h) {
  constexpr int LKS = LKP + 8;
  const int p = by & 1, bb = by >> 1;
  const int tid = threadIdx.x, l = tid & 63, w = tid >> 6;
  const size_t qrow0 = (size_t)(p * 128 + bb) * LQ;
  const u16* Qg = Q + qrow0 * 768 + h * 64;
  const u16* Kg = KVb + (size_t)bb * LK * 1536 + h * 64;
  const u16* Vg = Kg + 768;

  u16* Qs = (u16*)smraw;                      // LQP*64
  u16* KV = Qs + LQP * 64;                    // 64*LKS
  u16* Ss = KV + 64 * LKS;                    // LQP*LKS
  int* tokLds = (int*)(Ss + LQP * LKS);       // LKP (MASK only)

  for (int s = tid; s < LQP * 8; s += 256) {
    int row = s >> 3, d8 = (s & 7) ^ (row & 7);
    int gr = row < LQ ? row : LQ - 1;
    gload16(Qg + (size_t)gr * 768 + d8 * 8, &Qs[s * 8]);
  }
  for (int s = tid; s < LKP * 8; s += 256) {
    int row = s >> 3, d8 = (s & 7) ^ (row & 7);
    int gr = row < LK ? row : LK - 1;
    gload16(Kg + (size_t)gr * 1536 + d8 * 8, &KV[s * 8]);
  }
  if (MASK)
    for (int c = tid; c < LKP; c += 256) tokLds[c] = (c < LK) ? toks[bb * LK + c] : 1;
  __syncthreads();

  for (int nt = w; nt < LKP / 16; nt += 4) {
    const int brow = nt * 16 + (l & 15);
#pragma unroll
    for (int mt = 0; mt < LQP / 16; ++mt) {
      const int arow = mt * 16 + (l & 15);
      f32x4 a_ = {0.f, 0.f, 0.f, 0.f};
#pragma unroll
      for (int kk = 0; kk < 2; ++kk) {
        bf16x8 av = *(const bf16x8*)&Qs[arow * 64 + (((kk * 4 + (l >> 4)) ^ (arow & 7)) << 3)];
        bf16x8 bv = *(const bf16x8*)&KV[brow * 64 + (((kk * 4 + (l >> 4)) ^ (brow & 7)) << 3)];
        a_ = mfma16(av, bv, a_);
      }
      const int r0 = mt * 16 + (l >> 4) * 4, cc = nt * 16 + (l & 15);
#pragma unroll
      for (int j = 0; j < 4; ++j) Ss[(r0 + j) * LKS + cc] = f2b(a_[j]);
    }
  }
  __syncthreads();

  {
    const int kcol = tid & 31, d8 = tid >> 5;
#pragma unroll
    for (int kb = 0; kb < LKP / 32; ++kb) {
      const int k = kb * 32 + kcol;
      alignas(16) u16 tmp[8] = {0, 0, 0, 0, 0, 0, 0, 0};
      if (k < LK) *(uint4*)tmp = *(const uint4*)(Vg + (size_t)k * 1536 + d8 * 8);
#pragma unroll
      for (int j = 0; j < 8; ++j) KV[(d8 * 8 + j) * LKS + k] = tmp[j];
    }
  }
  constexpr int NCH = (LKP + 63) / 64;
  for (int r = w; r < LQ; r += 4) {
    float sv[NCH];
    float mx = -INFINITY;
#pragma unroll
    for (int i = 0; i < NCH; ++i) {
      int c = l + (i << 6);
      float s = -INFINITY;
      if (c < LK) {
        s = b2f(Ss[r * LKS + c]);
        if (MASK && tokLds[c] == 0) s = -1e9f;
      }
      sv[i] = s;
      mx = fmaxf(mx, s);
    }
    for (int d = 1; d < 64; d <<= 1) mx = fmaxf(mx, __shfl_xor(mx, d));
    float sum = 0.f;
#pragma unroll
    for (int i = 0; i < NCH; ++i) { float e = __expf(sv[i] - mx); sv[i] = e; sum += e; }
    for (int d = 1; d < 64; d <<= 1) sum += __shfl_xor(sum, d);
    const float inv = 1.0f / sum;
#pragma unroll
    for (int i = 0; i < NCH; ++i) {
      int c = l + (i << 6);
      if (c < LKP) Ss[r * LKS + c] = f2b(sv[i] * inv);
    }
  }
  __syncthreads();

  for (int mt = w; mt < LQP / 16; mt += 4) {
    const int arow = mt * 16 + (l & 15);
#pragma unroll
    for (int nt = 0; nt < 4; ++nt) {
      f32x4 a_ = {0.f, 0.f, 0.f, 0.f};
#pragma unroll
      for (int kk = 0; kk < LKP; kk += 32) {
        bf16x8 av = *(const bf16x8*)&Ss[arow * LKS + kk + (l >> 4) * 8];
        bf16x8 bv = *(const bf16x8*)&KV[(nt * 16 + (l & 15)) * LKS + kk + (l >> 4) * 8];
        a_ = mfma16(av, bv, a_);
      }
      const int r0 = mt * 16 + (l >> 4) * 4, c16 = l & 15;
#pragma unroll
      for (int j = 0; j < 4; ++j) {
        int r = r0 + j;
        if (r < LQ) O[(qrow0 + r) * 768 + h * 64 + nt * 16 + c16] = f2b(a_[j]);
      }
    }
  }
}

// fused attention: grid (12, 512); y<256 image, y>=256 text (text blocks backfill as image retires)
__global__ __launch_bounds__(256) void attn_fused(const u16* __restrict__ Qb, const u16* __restrict__ KVb_i,
                                                  const u16* __restrict__ KVb_t, const int* __restrict__ toks,
                                                  u16* __restrict__ qn) {
  extern __shared__ char sm[];
  const int by = blockIdx.y, h = blockIdx.x;
  if (by < 256) {
    attn_body<64, 224, 60, 197, false>(sm, Qb, KVb_i, nullptr, qn, by, h);
  } else {
    attn_body<32, 64, 20, 64, true>(sm, Qb + (size_t)15360 * 768, KVb_t, toks,
                                    qn + (size_t)15360 * 768, by - 256, h);
  }
}

// ---------------------------------------------------------------
extern "C" void kernel_launch(void* const* d_in, const int* in_sizes, int n_in,
                              void* d_out, int out_size, void* d_ws, size_t ws_size,
                              hipStream_t stream) {
  (void)in_sizes; (void)n_in; (void)out_size; (void)ws_size;
  const float* image_feats = (const float*)d_in[0];
  const float* image_att = (const float*)d_in[1];
  const float* text_feats = (const float*)d_in[2];
  const float* text_att = (const float*)d_in[3];
  const int* tokens = (const int*)d_in[4];
  const float* bn_img_g = (const float*)d_in[5];
  const float* bn_img_b = (const float*)d_in[6];
  const float* bn_img_m = (const float*)d_in[7];
  const float* bn_img_v = (const float*)d_in[8];
  const float* bn_txt_g = (const float*)d_in[9];
  const float* bn_txt_b = (const float*)d_in[10];
  const float* bn_txt_m = (const float*)d_in[11];
  const float* bn_txt_v = (const float*)d_in[12];
  const float* ln1_g = (const float*)d_in[13];
  const float* ln1_b = (const float*)d_in[14];
  const float* ln2_g = (const float*)d_in[15];
  const float* ln2_b = (const float*)d_in[16];
  const float* Wq = (const float*)d_in[17];
  const float* Wk = (const float*)d_in[18];
  const float* Wv = (const float*)d_in[19];
  const float* Wo = (const float*)d_in[20];
  const float* bq = (const float*)d_in[21];
  const float* bk = (const float*)d_in[22];
  const float* bv = (const float*)d_in[23];
  const float* bo = (const float*)d_in[24];
  const float* W1 = (const float*)d_in[25];
  const float* b1 = (const float*)d_in[26];
  const float* W2 = (const float*)d_in[27];
  const float* b2 = (const float*)d_in[28];

  float* out = (float*)d_out;
  char* wsp = (char*)d_ws;
  size_t off = 0;
  auto alloc = [&](size_t bytes) -> void* {
    void* p = wsp + off;
    off += (bytes + 255) & ~(size_t)255;
    return p;
  };
  // weights
  u16* WqT = (u16*)alloc(768 * 768 * 2);
  u16* WkvT = (u16*)alloc((size_t)1536 * 768 * 2);
  u16* WoT = (u16*)alloc(768 * 768 * 2);
  u16* W1T = (u16*)alloc((size_t)768 * 3072 * 2);
  u16* W2T = (u16*)alloc((size_t)768 * 3072 * 2);
  float* bkv = (float*)alloc(1536 * 4);
  // combined K/V row space: rows 0..25215 image, 25216..33407 text
  char* kvbase = (char*)(wsp + off);
  u16* kn = (u16*)alloc((size_t)33408 * 768 * 2);
  u16* KVb = (u16*)alloc((size_t)33408 * 1536 * 2);
  u16* KVb_t = KVb + (size_t)25216 * 1536;
  u16* gb = (u16*)kvbase;  // FF intermediate [20480 x 3072] bf16 (aliases dead K/V region)
  int* sel_i = (int*)alloc(2 * 128 * 60 * 4);
  int* sel_t = (int*)alloc(2 * 128 * 20 * 4);
  u16* qn = (u16*)alloc((size_t)20480 * 768 * 2);
  float* xs = (float*)alloc((size_t)20480 * 768 * 4);
  u16* Qb = (u16*)alloc((size_t)20480 * 768 * 2);

  const dim3 tb(32, 8);
  transpose_all<<<6913, tb, 0, stream>>>(Wq, Wk, Wv, Wo, W1, W2, bk, bv, WqT, WkvT, WoT, W1T, W2T, bkv);

  bn_both<<<dim3(128, 2), 256, 0, stream>>>(image_feats, text_feats, bn_img_g, bn_img_b, bn_img_m, bn_img_v,
                                            bn_txt_g, bn_txt_b, bn_txt_m, bn_txt_v, out);
  topk_both<<<dim3(128, 2), 256, 0, stream>>>(image_att, text_att, sel_i, sel_t);

  // LN1 of both modalities into combined kn, then ONE fused K+V projection (M=33408, N=1536)
  ln1_both<<<33408 / 4, 256, 0, stream>>>(image_feats, text_feats, ln1_g, ln1_b, kn);
  gemm_bt<EPI_PLAIN><<<dim3(12, 261), 256, 0, stream>>>(kn, WkvT, bkv, nullptr, KVb, 33408, 1536, 768);

  // both gathers in one launch
  gather_both<<<dim3(80, 256), 128, 0, stream>>>(sel_i, sel_t, kn, image_feats, text_feats, qn, xs);

  // Q projection (combined, pre-scaled by 1/sqrt(64))
  gemm_bt<EPI_QSCALE><<<dim3(6, 160), 256, 0, stream>>>(qn, WqT, bq, nullptr, Qb, 20480, 768, 768);

  // fused attention (img + txt in one launch; dynamic LDS sized for the image variant)
  // img: Qs 64*64 + KV 64*232 + Ss 64*232 u16 = 67584 B
  attn_fused<<<dim3(12, 512), 256, 67584, stream>>>(Qb, KVb, KVb_t, tokens, qn);

  // x1 = xs + att@Wo + bo   (in-place on xs)
  gemm_bt<EPI_RES_FADD><<<dim3(6, 160), 256, 0, stream>>>(qn, WoT, bo, xs, xs, 20480, 768, 768);
  // h = LN2(x1)
  ln_rows<<<20480 / 4, 256, 0, stream>>>(xs, ln2_g, ln2_b, Qb);
  // gb = gelu(h@W1 + b1)
  gemm_bt<EPI_GELU><<<dim3(24, 160), 256, 0, stream>>>(Qb, W1T, b1, nullptr, gb, 20480, 3072, 768);
  // out = x1 + gb@W2 + b2
  gemm_bt<EPI_RES_OUT><<<dim3(6, 160), 256, 0, stream>>>(gb, W2T, b2, xs, out + 196608, 20480, 768, 3072);
}

// Round 18
// 693.719 us; speedup vs baseline: 1.0275x; 1.0275x over previous
//
#include <hip/hip_runtime.h>

typedef unsigned short u16;
typedef __bf16 bf16x8 __attribute__((ext_vector_type(8)));
typedef float f32x4 __attribute__((ext_vector_type(4)));

__device__ __forceinline__ float b2f(u16 u) { return __builtin_bit_cast(float, (unsigned)u << 16); }
__device__ __forceinline__ u16 f2b(float f) {
  unsigned x = __builtin_bit_cast(unsigned, f);
  x += 0x7fffu + ((x >> 16) & 1u);
  return (u16)(x >> 16);
}

__device__ __forceinline__ void gload16(const u16* g, u16* l) {
  auto gp = (__attribute__((address_space(1))) void*)(void*)const_cast<u16*>(g);
  auto lp = (__attribute__((address_space(3))) void*)(void*)l;
  __builtin_amdgcn_global_load_lds(gp, lp, 16, 0, 0);
}

__device__ __forceinline__ f32x4 mfma16(bf16x8 a, bf16x8 b, f32x4 c) {
  return __builtin_amdgcn_mfma_f32_16x16x32_bf16(a, b, c, 0, 0, 0);
}

// overflow-stable tanh-form GELU (hardware v_exp_f32)
__device__ __forceinline__ float gelu_fast(float v) {
  float u = v * (0.7978845608028654f + 0.03567740813636141f * v * v);
  float e = __expf(2.0f * u);
  float th = 1.0f - 2.0f / (e + 1.0f);
  return 0.5f * v * (1.0f + th);
}

// ---------------- ALL weight transposes (f32 -> bf16) in ONE launch ----------------
// tiles: [0,2304) Wq/Wk/Wv/Wo (24x24 each); [2304,4608) W1 (96x24); [4608,6912) W2 (24x96)
__global__ __launch_bounds__(256) void transpose_all(const float* __restrict__ Wq, const float* __restrict__ Wk,
                                                     const float* __restrict__ Wv, const float* __restrict__ Wo,
                                                     const float* __restrict__ W1, const float* __restrict__ W2,
                                                     u16* __restrict__ WqT, u16* __restrict__ WkvT,
                                                     u16* __restrict__ WoT, u16* __restrict__ W1T,
                                                     u16* __restrict__ W2T) {
  __shared__ float tile[32][33];
  const int t = blockIdx.x;
  const float* in;
  u16* out;
  int R, C, tx, ty;
  if (t < 2304) {
    const int z = t / 576, r = t % 576;
    tx = r % 24; ty = r / 24; R = 768; C = 768;
    in = (z == 0) ? Wq : (z == 1) ? Wk : (z == 2) ? Wv : Wo;
    out = (z == 0) ? WqT : (z == 1) ? WkvT : (z == 2) ? (WkvT + (size_t)768 * 768) : WoT;
  } else if (t < 4608) {
    const int r = t - 2304;
    tx = r % 96; ty = r / 96; R = 768; C = 3072;
    in = W1; out = W1T;
  } else {
    const int r = t - 4608;
    tx = r % 24; ty = r / 24; R = 3072; C = 768;
    in = W2; out = W2T;
  }
  const int bx = tx * 32, by = ty * 32;
  const int x = threadIdx.x;
  for (int yy = threadIdx.y; yy < 32; yy += 8) tile[yy][x] = in[(size_t)(by + yy) * C + bx + x];
  __syncthreads();
  for (int yy = threadIdx.y; yy < 32; yy += 8) out[(size_t)(bx + yy) * R + by + x] = f2b(tile[x][yy]);
}

// ---------------- BN on row 0, both modalities in one launch (grid.y selects) ----------------
__global__ __launch_bounds__(256) void bn_both(const float* __restrict__ imgf, const float* __restrict__ txtf,
                                               const float* gi, const float* bi, const float* mi, const float* vi,
                                               const float* gt, const float* bt, const float* mt, const float* vt,
                                               float* __restrict__ out) {
  const int bb = blockIdx.x, z = blockIdx.y;
  const float* row = z ? (txtf + (size_t)bb * 64 * 768) : (imgf + (size_t)bb * 197 * 768);
  const float *g = z ? gt : gi, *b = z ? bt : bi, *m = z ? mt : mi, *v = z ? vt : vi;
  float* o = out + (size_t)z * 98304 + bb * 768;
  for (int d = threadIdx.x; d < 768; d += 256) {
    float x = row[d];
    o[d] = (x - m[d]) * (1.0f / sqrtf(v[d] + 1e-5f)) * g[d] + b[d];
  }
}

// ---------------- stable top-k, both modalities in one launch ----------------
__global__ __launch_bounds__(256) void topk_both(const float* __restrict__ img_score,
                                                 const float* __restrict__ txt_score,
                                                 int* __restrict__ sel_i, int* __restrict__ sel_t) {
  __shared__ float s[256];
  const int b = blockIdx.x, z = blockIdx.y;
  const float* score = z ? txt_score : img_score;
  int* sel = z ? sel_t : sel_i;
  const int L = z ? 64 : 197, Ksel = z ? 19 : 59, Lq = z ? 20 : 60;
  const int stride2 = 128 * Lq;
  for (int i = threadIdx.x; i < L; i += 256) {
    float v = score[b * L + i];
    s[i] = (i == 0) ? 0.0f : v;
  }
  __syncthreads();
  for (int i = threadIdx.x; i < L; i += 256) {
    float si = s[i];
    int rank = 0;
    for (int j = 0; j < L; ++j) {
      float sj = s[j];
      rank += (sj > si) || (sj == si && j < i);
    }
    if (rank < Ksel) sel[b * Lq + rank + 1] = i;
    else if (rank < 2 * Ksel) sel[stride2 + b * Lq + (rank - Ksel) + 1] = i;
  }
  if (threadIdx.x == 0) { sel[b * Lq] = 0; sel[stride2 + b * Lq] = 0; }
}

// ---------------- LN1 over the combined 33408-row space (image rows then text rows) ----------------
__global__ __launch_bounds__(256) void ln1_both(const float* __restrict__ imgf, const float* __restrict__ txtf,
                                                const float* g, const float* b, u16* __restrict__ out) {
  const int row = blockIdx.x * 4 + (threadIdx.x >> 6);
  const int l = threadIdx.x & 63;
  const float* xr = (row < 25216) ? (imgf + (size_t)row * 768) : (txtf + (size_t)(row - 25216) * 768);
  float v[12]; float s = 0.f;
#pragma unroll
  for (int i = 0; i < 12; ++i) { v[i] = xr[l + i * 64]; s += v[i]; }
  for (int d = 1; d < 64; d <<= 1) s += __shfl_xor(s, d);
  const float mu = s * (1.0f / 768.0f);
  float q = 0.f;
#pragma unroll
  for (int i = 0; i < 12; ++i) { float t = v[i] - mu; q += t * t; }
  for (int d = 1; d < 64; d <<= 1) q += __shfl_xor(q, d);
  const float rs = 1.0f / sqrtf(q * (1.0f / 768.0f) + 1e-5f);
#pragma unroll
  for (int i = 0; i < 12; ++i) {
    int c = l + i * 64;
    out[(size_t)row * 768 + c] = f2b((v[i] - mu) * rs * g[c] + b[c]);
  }
}

// ---------------- LayerNorm (f32 in -> bf16 out), one wave per 768-row ----------------
__global__ __launch_bounds__(256) void ln_rows(const float* __restrict__ x, const float* g, const float* b,
                                               u16* __restrict__ out) {
  const int row = blockIdx.x * 4 + (threadIdx.x >> 6);
  const int l = threadIdx.x & 63;
  const float* xr = x + (size_t)row * 768;
  float v[12]; float s = 0.f;
#pragma unroll
  for (int i = 0; i < 12; ++i) { v[i] = xr[l + i * 64]; s += v[i]; }
  for (int d = 1; d < 64; d <<= 1) s += __shfl_xor(s, d);
  const float mu = s * (1.0f / 768.0f);
  float q = 0.f;
#pragma unroll
  for (int i = 0; i < 12; ++i) { float t = v[i] - mu; q += t * t; }
  for (int d = 1; d < 64; d <<= 1) q += __shfl_xor(q, d);
  const float rs = 1.0f / sqrtf(q * (1.0f / 768.0f) + 1e-5f);
#pragma unroll
  for (int i = 0; i < 12; ++i) {
    int c = l + i * 64;
    out[(size_t)row * 768 + c] = f2b((v[i] - mu) * rs * g[c] + b[c]);
  }
}

// ---------------- both gathers in one launch: bx<60 image part, else text ----------------
__global__ __launch_bounds__(128) void gather_both(const int* __restrict__ sel_i, const int* __restrict__ sel_t,
                                                   const u16* __restrict__ kn, const float* __restrict__ imgf,
                                                   const float* __restrict__ txtf, u16* __restrict__ qn,
                                                   float* __restrict__ xs) {
  const int bx = blockIdx.x, by = blockIdx.y;
  const int p = by >> 7, b = by & 127;
  const int* sel;
  const u16* knp;
  const float* feats;
  int Lq, Lsrc, q, rowbase;
  if (bx < 60) {
    sel = sel_i; knp = kn; feats = imgf; Lq = 60; Lsrc = 197; q = bx; rowbase = 0;
  } else {
    sel = sel_t; knp = kn + (size_t)25216 * 768; feats = txtf; Lq = 20; Lsrc = 64; q = bx - 60; rowbase = 15360;
  }
  const int prow = (p * 128 + b) * Lq + q;           // row within this modality's sel/compact space
  const int row = rowbase + prow;                    // row in the combined 20480-row space
  const int src = sel[prow];
  const uint4* sq = (const uint4*)(knp + ((size_t)b * Lsrc + src) * 768);
  uint4* dq = (uint4*)(qn + (size_t)row * 768);
  for (int c = threadIdx.x; c < 96; c += 128) dq[c] = sq[c];
  const float4* sx = (const float4*)(feats + ((size_t)b * Lsrc + src) * 768);
  float4* dx = (float4*)(xs + (size_t)row * 768);
  for (int c = threadIdx.x; c < 192; c += 128) dx[c] = sx[c];
}

enum { EPI_PLAIN = 0, EPI_QSCALE = 1, EPI_GELU = 2, EPI_RES_FADD = 3, EPI_RES_OUT = 4 };

template <int EPI>
__device__ __forceinline__ void epi_write(float v, size_t off, void* outp, const float* res) {
  if constexpr (EPI == EPI_QSCALE) {
    ((u16*)outp)[off] = f2b(v * 0.125f);
  } else if constexpr (EPI == EPI_GELU) {
    ((u16*)outp)[off] = f2b(gelu_fast(v));
  } else if constexpr (EPI == EPI_RES_FADD || EPI == EPI_RES_OUT) {
    ((float*)outp)[off] = v + res[off];
  } else {
    ((u16*)outp)[off] = f2b(v);
  }
}

// ---------------- GEMM 128^2, BK=32, 2-phase dbuf, 32KB LDS; bounds(256,4) [best known: R13/R15] ----------------
// Residency bound by the unified VGPR+AGPR file (~124/wave) -> 4 waves/SIMD max; (256,5) spills (R12).
template <int EPI>
__global__ __launch_bounds__(256, 4) void gemm_bt(const u16* __restrict__ A, const u16* __restrict__ Bt,
                                                  const float* __restrict__ bias, const float* __restrict__ res,
                                                  void* __restrict__ outp, int M, int N, int K) {
  __shared__ alignas(16) u16 As[2][4096];
  __shared__ alignas(16) u16 Bs[2][4096];
  const int tid = threadIdx.x, l = tid & 63, w = tid >> 6;
  const int nwg = gridDim.x * gridDim.y;
  int lin = blockIdx.y * gridDim.x + blockIdx.x;
  const int q8 = nwg >> 3, r8 = nwg & 7;
  const int xcd = lin & 7, pos = lin >> 3;
  const int nl = (xcd < r8) ? (xcd * (q8 + 1) + pos) : (r8 * (q8 + 1) + (xcd - r8) * q8 + pos);
  const int m0 = (nl / gridDim.x) * 128, n0 = (nl % gridDim.x) * 128;
  const int wm = (w & 1) * 64, wn = (w >> 1) * 64;
  f32x4 acc[4][4] = {};

  int arow_g[2], ach_g[2];
#pragma unroll
  for (int p = 0; p < 2; ++p) {
    const int s = p * 256 + tid;
    const int rl = s >> 3, v = (s & 7) ^ (rl & 7);
    arow_g[p] = (v >> 2) * 64 + rl;
    ach_g[p] = (v & 3) * 8;
  }
  auto STAGE = [&](int buf, int k0) {
#pragma unroll
    for (int p = 0; p < 2; ++p) {
      const int s = p * 256 + tid;
      gload16(A + (size_t)(m0 + arow_g[p]) * K + k0 + ach_g[p], &As[buf][s * 8]);
      gload16(Bt + (size_t)(n0 + arow_g[p]) * K + k0 + ach_g[p], &Bs[buf][s * 8]);
    }
  };  // 4 VMEM / thread / tile

  const int c = l >> 4;
  auto COMPUTE = [&](int buf) {
    bf16x8 af[4], bfr[4];
#pragma unroll
    for (int i = 0; i < 4; ++i) {
      const int arow = wm + i * 16 + (l & 15);
      const int slot = (c | ((arow >> 6) << 2)) ^ (arow & 7);
      af[i] = *(const bf16x8*)&As[buf][(arow & 63) * 64 + slot * 8];
      const int brow = wn + i * 16 + (l & 15);
      const int slotb = (c | ((brow >> 6) << 2)) ^ (brow & 7);
      bfr[i] = *(const bf16x8*)&Bs[buf][(brow & 63) * 64 + slotb * 8];
    }
    __builtin_amdgcn_s_setprio(1);
#pragma unroll
    for (int mi = 0; mi < 4; ++mi)
#pragma unroll
      for (int ni = 0; ni < 4; ++ni) acc[mi][ni] = mfma16(af[mi], bfr[ni], acc[mi][ni]);
    __builtin_amdgcn_s_setprio(0);
  };

  const int NT = K >> 5;
  STAGE(0, 0);
  int cur = 0;
  for (int t = 0; t < NT - 1; ++t) {
    STAGE(cur ^ 1, (t + 1) << 5);
    asm volatile("s_waitcnt vmcnt(4)" ::: "memory");
    __builtin_amdgcn_sched_barrier(0);
    __builtin_amdgcn_s_barrier();
    COMPUTE(cur);
    __builtin_amdgcn_s_barrier();
    cur ^= 1;
  }
  asm volatile("s_waitcnt vmcnt(0)" ::: "memory");
  __builtin_amdgcn_sched_barrier(0);
  __builtin_amdgcn_s_barrier();
  COMPUTE(cur);

  const int r4 = (l >> 4) * 4, c16 = l & 15;
#pragma unroll
  for (int mi = 0; mi < 4; ++mi)
#pragma unroll
    for (int ni = 0; ni < 4; ++ni) {
      const int gn = n0 + wn + ni * 16 + c16;
      const float bia = bias[gn];
#pragma unroll
      for (int j = 0; j < 4; ++j) {
        const int gm = m0 + wm + mi * 16 + r4 + j;
        epi_write<EPI>(acc[mi][ni][j] + bia, (size_t)gm * N + gn, outp, res);
      }
    }
}

// ---------------- attention: one WG per (head, part*batch); K/V interleaved [row][1536] ----------------
template <int LQP, int LKP, int LQ, int LK, bool MASK>
__global__ __launch_bounds__(256) void attn2(const u16* __restrict__ Q, const u16* __restrict__ KVb,
                                             const int* __restrict__ toks, u16* __restrict__ O) {
  constexpr int LKS = LKP + 8;
  const int h = blockIdx.x, by = blockIdx.y;
  const int p = by & 1, bb = by >> 1;
  const int tid = threadIdx.x, l = tid & 63, w = tid >> 6;
  const size_t qrow0 = (size_t)(p * 128 + bb) * LQ;
  const u16* Qg = Q + qrow0 * 768 + h * 64;
  const u16* Kg = KVb + (size_t)bb * LK * 1536 + h * 64;
  const u16* Vg = Kg + 768;

  __shared__ alignas(16) u16 Qs[LQP * 64];
  __shared__ alignas(16) u16 KV[64 * LKS];
  __shared__ alignas(16) u16 Ss[LQP * LKS];
  __shared__ int tokLds[MASK ? LKP : 1];

  for (int s = tid; s < LQP * 8; s += 256) {
    int row = s >> 3, d8 = (s & 7) ^ (row & 7);
    int gr = row < LQ ? row : LQ - 1;
    gload16(Qg + (size_t)gr * 768 + d8 * 8, &Qs[s * 8]);
  }
  for (int s = tid; s < LKP * 8; s += 256) {
    int row = s >> 3, d8 = (s & 7) ^ (row & 7);
    int gr = row < LK ? row : LK - 1;
    gload16(Kg + (size_t)gr * 1536 + d8 * 8, &KV[s * 8]);
  }
  if (MASK)
    for (int c = tid; c < LKP; c += 256) tokLds[c] = (c < LK) ? toks[bb * LK + c] : 1;
  __syncthreads();

  for (int nt = w; nt < LKP / 16; nt += 4) {
    const int brow = nt * 16 + (l & 15);
#pragma unroll
    for (int mt = 0; mt < LQP / 16; ++mt) {
      const int arow = mt * 16 + (l & 15);
      f32x4 a_ = {0.f, 0.f, 0.f, 0.f};
#pragma unroll
      for (int kk = 0; kk < 2; ++kk) {
        bf16x8 av = *(const bf16x8*)&Qs[arow * 64 + (((kk * 4 + (l >> 4)) ^ (arow & 7)) << 3)];
        bf16x8 bv = *(const bf16x8*)&KV[brow * 64 + (((kk * 4 + (l >> 4)) ^ (brow & 7)) << 3)];
        a_ = mfma16(av, bv, a_);
      }
      const int r0 = mt * 16 + (l >> 4) * 4, cc = nt * 16 + (l & 15);
#pragma unroll
      for (int j = 0; j < 4; ++j) Ss[(r0 + j) * LKS + cc] = f2b(a_[j]);
    }
  }
  __syncthreads();

  {
    const int kcol = tid & 31, d8 = tid >> 5;
#pragma unroll
    for (int kb = 0; kb < LKP / 32; ++kb) {
      const int k = kb * 32 + kcol;
      alignas(16) u16 tmp[8] = {0, 0, 0, 0, 0, 0, 0, 0};
      if (k < LK) *(uint4*)tmp = *(const uint4*)(Vg + (size_t)k * 1536 + d8 * 8);
#pragma unroll
      for (int j = 0; j < 8; ++j) KV[(d8 * 8 + j) * LKS + k] = tmp[j];
    }
  }
  constexpr int NCH = (LKP + 63) / 64;
  for (int r = w; r < LQ; r += 4) {
    float sv[NCH];
    float mx = -INFINITY;
#pragma unroll
    for (int i = 0; i < NCH; ++i) {
      int c = l + (i << 6);
      float s = -INFINITY;
      if (c < LK) {
        s = b2f(Ss[r * LKS + c]);
        if (MASK && tokLds[c] == 0) s = -1e9f;
      }
      sv[i] = s;
      mx = fmaxf(mx, s);
    }
    for (int d = 1; d < 64; d <<= 1) mx = fmaxf(mx, __shfl_xor(mx, d));
    float sum = 0.f;
#pragma unroll
    for (int i = 0; i < NCH; ++i) { float e = __expf(sv[i] - mx); sv[i] = e; sum += e; }
    for (int d = 1; d < 64; d <<= 1) sum += __shfl_xor(sum, d);
    const float inv = 1.0f / sum;
#pragma unroll
    for (int i = 0; i < NCH; ++i) {
      int c = l + (i << 6);
      if (c < LKP) Ss[r * LKS + c] = f2b(sv[i] * inv);
    }
  }
  __syncthreads();

  for (int mt = w; mt < LQP / 16; mt += 4) {
    const int arow = mt * 16 + (l & 15);
#pragma unroll
    for (int nt = 0; nt < 4; ++nt) {
      f32x4 a_ = {0.f, 0.f, 0.f, 0.f};
#pragma unroll
      for (int kk = 0; kk < LKP; kk += 32) {
        bf16x8 av = *(const bf16x8*)&Ss[arow * LKS + kk + (l >> 4) * 8];
        bf16x8 bv = *(const bf16x8*)&KV[(nt * 16 + (l & 15)) * LKS + kk + (l >> 4) * 8];
        a_ = mfma16(av, bv, a_);
      }
      const int r0 = mt * 16 + (l >> 4) * 4, c16 = l & 15;
#pragma unroll
      for (int j = 0; j < 4; ++j) {
        int r = r0 + j;
        if (r < LQ) O[(qrow0 + r) * 768 + h * 64 + nt * 16 + c16] = f2b(a_[j]);
      }
    }
  }
}

// ---------------------------------------------------------------
extern "C" void kernel_launch(void* const* d_in, const int* in_sizes, int n_in,
                              void* d_out, int out_size, void* d_ws, size_t ws_size,
                              hipStream_t stream) {
  (void)in_sizes; (void)n_in; (void)out_size; (void)ws_size;
  const float* image_feats = (const float*)d_in[0];
  const float* image_att = (const float*)d_in[1];
  const float* text_feats = (const float*)d_in[2];
  const float* text_att = (const float*)d_in[3];
  const int* tokens = (const int*)d_in[4];
  const float* bn_img_g = (const float*)d_in[5];
  const float* bn_img_b = (const float*)d_in[6];
  const float* bn_img_m = (const float*)d_in[7];
  const float* bn_img_v = (const float*)d_in[8];
  const float* bn_txt_g = (const float*)d_in[9];
  const float* bn_txt_b = (const float*)d_in[10];
  const float* bn_txt_m = (const float*)d_in[11];
  const float* bn_txt_v = (const float*)d_in[12];
  const float* ln1_g = (const float*)d_in[13];
  const float* ln1_b = (const float*)d_in[14];
  const float* ln2_g = (const float*)d_in[15];
  const float* ln2_b = (const float*)d_in[16];
  const float* Wq = (const float*)d_in[17];
  const float* Wk = (const float*)d_in[18];
  const float* Wv = (const float*)d_in[19];
  const float* Wo = (const float*)d_in[20];
  const float* bq = (const float*)d_in[21];
  const float* bk = (const float*)d_in[22];
  const float* bv = (const float*)d_in[23];
  const float* bo = (const float*)d_in[24];
  const float* W1 = (const float*)d_in[25];
  const float* b1 = (const float*)d_in[26];
  const float* W2 = (const float*)d_in[27];
  const float* b2 = (const float*)d_in[28];

  float* out = (float*)d_out;
  char* wsp = (char*)d_ws;
  size_t off = 0;
  auto alloc = [&](size_t bytes) -> void* {
    void* p = wsp + off;
    off += (bytes + 255) & ~(size_t)255;
    return p;
  };
  // weights
  u16* WqT = (u16*)alloc(768 * 768 * 2);
  u16* WkvT = (u16*)alloc((size_t)1536 * 768 * 2);  // rows 0-767 = Wk^T, 768-1535 = Wv^T
  u16* WoT = (u16*)alloc(768 * 768 * 2);
  u16* W1T = (u16*)alloc((size_t)768 * 3072 * 2);
  u16* W2T = (u16*)alloc((size_t)768 * 3072 * 2);
  float* bkv = (float*)alloc(1536 * 4);
  // combined K/V row space: rows 0..25215 image, 25216..33407 text (33408 = 261*128)
  char* kvbase = (char*)(wsp + off);
  u16* kn = (u16*)alloc((size_t)33408 * 768 * 2);
  u16* KVb = (u16*)alloc((size_t)33408 * 1536 * 2);  // [row][0:768]=K, [768:1536]=V
  u16* KVb_t = KVb + (size_t)25216 * 1536;
  u16* gb = (u16*)kvbase;  // FF intermediate [20480 x 3072] bf16 = 126MB (aliases dead K/V region)
  int* sel_i = (int*)alloc(2 * 128 * 60 * 4);
  int* sel_t = (int*)alloc(2 * 128 * 20 * 4);
  u16* qn = (u16*)alloc((size_t)20480 * 768 * 2);
  float* xs = (float*)alloc((size_t)20480 * 768 * 4);
  u16* Qb = (u16*)alloc((size_t)20480 * 768 * 2);

  const dim3 tb(32, 8);
  transpose_all<<<6912, tb, 0, stream>>>(Wq, Wk, Wv, Wo, W1, W2, WqT, WkvT, WoT, W1T, W2T);
  hipMemcpyAsync(bkv, bk, 768 * 4, hipMemcpyDeviceToDevice, stream);
  hipMemcpyAsync(bkv + 768, bv, 768 * 4, hipMemcpyDeviceToDevice, stream);

  bn_both<<<dim3(128, 2), 256, 0, stream>>>(image_feats, text_feats, bn_img_g, bn_img_b, bn_img_m, bn_img_v,
                                            bn_txt_g, bn_txt_b, bn_txt_m, bn_txt_v, out);
  topk_both<<<dim3(128, 2), 256, 0, stream>>>(image_att, text_att, sel_i, sel_t);

  // LN1 of both modalities into combined kn, then ONE fused K+V projection (M=33408, N=1536)
  ln1_both<<<33408 / 4, 256, 0, stream>>>(image_feats, text_feats, ln1_g, ln1_b, kn);
  gemm_bt<EPI_PLAIN><<<dim3(12, 261), 256, 0, stream>>>(kn, WkvT, bkv, nullptr, KVb, 33408, 1536, 768);

  // both gathers in one launch
  gather_both<<<dim3(80, 256), 128, 0, stream>>>(sel_i, sel_t, kn, image_feats, text_feats, qn, xs);

  // Q projection (combined, pre-scaled by 1/sqrt(64))
  gemm_bt<EPI_QSCALE><<<dim3(6, 160), 256, 0, stream>>>(qn, WqT, bq, nullptr, Qb, 20480, 768, 768);

  // attention (writes att-out into qn)
  attn2<64, 224, 60, 197, false><<<dim3(12, 256), 256, 0, stream>>>(Qb, KVb, nullptr, qn);
  attn2<32, 64, 20, 64, true><<<dim3(12, 256), 256, 0, stream>>>(Qb + (size_t)15360 * 768, KVb_t,
                                                                 tokens, qn + (size_t)15360 * 768);

  // x1 = xs + att@Wo + bo   (in-place on xs)
  gemm_bt<EPI_RES_FADD><<<dim3(6, 160), 256, 0, stream>>>(qn, WoT, bo, xs, xs, 20480, 768, 768);
  // h = LN2(x1)
  ln_rows<<<20480 / 4, 256, 0, stream>>>(xs, ln2_g, ln2_b, Qb);
  // gb = gelu(h@W1 + b1)
  gemm_bt<EPI_GELU><<<dim3(24, 160), 256, 0, stream>>>(Qb, W1T, b1, nullptr, gb, 20480, 3072, 768);
  // out = x1 + gb@W2 + b2
  gemm_bt<EPI_RES_OUT><<<dim3(6, 160), 256, 0, stream>>>(gb, W2T, b2, xs, out + 196608, 20480, 768, 3072);
}

// Round 19
// 690.294 us; speedup vs baseline: 1.0326x; 1.0050x over previous
//
#include <hip/hip_runtime.h>

typedef unsigned short u16;
typedef __bf16 bf16x8 __attribute__((ext_vector_type(8)));
typedef float f32x4 __attribute__((ext_vector_type(4)));

__device__ __forceinline__ float b2f(u16 u) { return __builtin_bit_cast(float, (unsigned)u << 16); }
__device__ __forceinline__ u16 f2b(float f) {
  unsigned x = __builtin_bit_cast(unsigned, f);
  x += 0x7fffu + ((x >> 16) & 1u);
  return (u16)(x >> 16);
}

__device__ __forceinline__ void gload16(const u16* g, u16* l) {
  auto gp = (__attribute__((address_space(1))) void*)(void*)const_cast<u16*>(g);
  auto lp = (__attribute__((address_space(3))) void*)(void*)l;
  __builtin_amdgcn_global_load_lds(gp, lp, 16, 0, 0);
}

__device__ __forceinline__ f32x4 mfma16(bf16x8 a, bf16x8 b, f32x4 c) {
  return __builtin_amdgcn_mfma_f32_16x16x32_bf16(a, b, c, 0, 0, 0);
}

// overflow-stable tanh-form GELU (hardware v_exp_f32)
__device__ __forceinline__ float gelu_fast(float v) {
  float u = v * (0.7978845608028654f + 0.03567740813636141f * v * v);
  float e = __expf(2.0f * u);
  float th = 1.0f - 2.0f / (e + 1.0f);
  return 0.5f * v * (1.0f + th);
}

// ---------------- ALL weight transposes + bkv assembly in ONE launch ----------------
// tiles: [0,2304) Wq/Wk/Wv/Wo; [2304,4608) W1; [4608,6912) W2; [6912] copies bk|bv -> bkv
__global__ __launch_bounds__(256) void transpose_all(const float* __restrict__ Wq, const float* __restrict__ Wk,
                                                     const float* __restrict__ Wv, const float* __restrict__ Wo,
                                                     const float* __restrict__ W1, const float* __restrict__ W2,
                                                     const float* __restrict__ bk, const float* __restrict__ bv,
                                                     u16* __restrict__ WqT, u16* __restrict__ WkvT,
                                                     u16* __restrict__ WoT, u16* __restrict__ W1T,
                                                     u16* __restrict__ W2T, float* __restrict__ bkv) {
  __shared__ float tile[32][33];
  const int t = blockIdx.x;
  if (t == 6912) {
    const int i = threadIdx.y * 32 + threadIdx.x;
    for (int c = i; c < 768; c += 256) {
      bkv[c] = bk[c];
      bkv[768 + c] = bv[c];
    }
    return;
  }
  const float* in;
  u16* out;
  int R, C, tx, ty;
  if (t < 2304) {
    const int z = t / 576, r = t % 576;
    tx = r % 24; ty = r / 24; R = 768; C = 768;
    in = (z == 0) ? Wq : (z == 1) ? Wk : (z == 2) ? Wv : Wo;
    out = (z == 0) ? WqT : (z == 1) ? WkvT : (z == 2) ? (WkvT + (size_t)768 * 768) : WoT;
  } else if (t < 4608) {
    const int r = t - 2304;
    tx = r % 96; ty = r / 96; R = 768; C = 3072;
    in = W1; out = W1T;
  } else {
    const int r = t - 4608;
    tx = r % 24; ty = r / 24; R = 3072; C = 768;
    in = W2; out = W2T;
  }
  const int bx = tx * 32, by = ty * 32;
  const int x = threadIdx.x;
  for (int yy = threadIdx.y; yy < 32; yy += 8) tile[yy][x] = in[(size_t)(by + yy) * C + bx + x];
  __syncthreads();
  for (int yy = threadIdx.y; yy < 32; yy += 8) out[(size_t)(bx + yy) * R + by + x] = f2b(tile[x][yy]);
}

// ---------------- BN on row 0, both modalities in one launch (grid.y selects) ----------------
__global__ __launch_bounds__(256) void bn_both(const float* __restrict__ imgf, const float* __restrict__ txtf,
                                               const float* gi, const float* bi, const float* mi, const float* vi,
                                               const float* gt, const float* bt, const float* mt, const float* vt,
                                               float* __restrict__ out) {
  const int bb = blockIdx.x, z = blockIdx.y;
  const float* row = z ? (txtf + (size_t)bb * 64 * 768) : (imgf + (size_t)bb * 197 * 768);
  const float *g = z ? gt : gi, *b = z ? bt : bi, *m = z ? mt : mi, *v = z ? vt : vi;
  float* o = out + (size_t)z * 98304 + bb * 768;
  for (int d = threadIdx.x; d < 768; d += 256) {
    float x = row[d];
    o[d] = (x - m[d]) * (1.0f / sqrtf(v[d] + 1e-5f)) * g[d] + b[d];
  }
}

// ---------------- stable top-k, both modalities in one launch ----------------
__global__ __launch_bounds__(256) void topk_both(const float* __restrict__ img_score,
                                                 const float* __restrict__ txt_score,
                                                 int* __restrict__ sel_i, int* __restrict__ sel_t) {
  __shared__ float s[256];
  const int b = blockIdx.x, z = blockIdx.y;
  const float* score = z ? txt_score : img_score;
  int* sel = z ? sel_t : sel_i;
  const int L = z ? 64 : 197, Ksel = z ? 19 : 59, Lq = z ? 20 : 60;
  const int stride2 = 128 * Lq;
  for (int i = threadIdx.x; i < L; i += 256) {
    float v = score[b * L + i];
    s[i] = (i == 0) ? 0.0f : v;
  }
  __syncthreads();
  for (int i = threadIdx.x; i < L; i += 256) {
    float si = s[i];
    int rank = 0;
    for (int j = 0; j < L; ++j) {
      float sj = s[j];
      rank += (sj > si) || (sj == si && j < i);
    }
    if (rank < Ksel) sel[b * Lq + rank + 1] = i;
    else if (rank < 2 * Ksel) sel[stride2 + b * Lq + (rank - Ksel) + 1] = i;
  }
  if (threadIdx.x == 0) { sel[b * Lq] = 0; sel[stride2 + b * Lq] = 0; }
}

// ---------------- LN1 over the combined 33408-row space (image rows then text rows) ----------------
__global__ __launch_bounds__(256) void ln1_both(const float* __restrict__ imgf, const float* __restrict__ txtf,
                                                const float* g, const float* b, u16* __restrict__ out) {
  const int row = blockIdx.x * 4 + (threadIdx.x >> 6);
  const int l = threadIdx.x & 63;
  const float* xr = (row < 25216) ? (imgf + (size_t)row * 768) : (txtf + (size_t)(row - 25216) * 768);
  float v[12]; float s = 0.f;
#pragma unroll
  for (int i = 0; i < 12; ++i) { v[i] = xr[l + i * 64]; s += v[i]; }
  for (int d = 1; d < 64; d <<= 1) s += __shfl_xor(s, d);
  const float mu = s * (1.0f / 768.0f);
  float q = 0.f;
#pragma unroll
  for (int i = 0; i < 12; ++i) { float t = v[i] - mu; q += t * t; }
  for (int d = 1; d < 64; d <<= 1) q += __shfl_xor(q, d);
  const float rs = 1.0f / sqrtf(q * (1.0f / 768.0f) + 1e-5f);
#pragma unroll
  for (int i = 0; i < 12; ++i) {
    int c = l + i * 64;
    out[(size_t)row * 768 + c] = f2b((v[i] - mu) * rs * g[c] + b[c]);
  }
}

// ---------------- LayerNorm (f32 in -> bf16 out), one wave per 768-row ----------------
__global__ __launch_bounds__(256) void ln_rows(const float* __restrict__ x, const float* g, const float* b,
                                               u16* __restrict__ out) {
  const int row = blockIdx.x * 4 + (threadIdx.x >> 6);
  const int l = threadIdx.x & 63;
  const float* xr = x + (size_t)row * 768;
  float v[12]; float s = 0.f;
#pragma unroll
  for (int i = 0; i < 12; ++i) { v[i] = xr[l + i * 64]; s += v[i]; }
  for (int d = 1; d < 64; d <<= 1) s += __shfl_xor(s, d);
  const float mu = s * (1.0f / 768.0f);
  float q = 0.f;
#pragma unroll
  for (int i = 0; i < 12; ++i) { float t = v[i] - mu; q += t * t; }
  for (int d = 1; d < 64; d <<= 1) q += __shfl_xor(q, d);
  const float rs = 1.0f / sqrtf(q * (1.0f / 768.0f) + 1e-5f);
#pragma unroll
  for (int i = 0; i < 12; ++i) {
    int c = l + i * 64;
    out[(size_t)row * 768 + c] = f2b((v[i] - mu) * rs * g[c] + b[c]);
  }
}

// ---------------- both gathers in one launch: bx<60 image part, else text ----------------
__global__ __launch_bounds__(128) void gather_both(const int* __restrict__ sel_i, const int* __restrict__ sel_t,
                                                   const u16* __restrict__ kn, const float* __restrict__ imgf,
                                                   const float* __restrict__ txtf, u16* __restrict__ qn,
                                                   float* __restrict__ xs) {
  const int bx = blockIdx.x, by = blockIdx.y;
  const int p = by >> 7, b = by & 127;
  const int* sel;
  const u16* knp;
  const float* feats;
  int Lq, Lsrc, q, rowbase;
  if (bx < 60) {
    sel = sel_i; knp = kn; feats = imgf; Lq = 60; Lsrc = 197; q = bx; rowbase = 0;
  } else {
    sel = sel_t; knp = kn + (size_t)25216 * 768; feats = txtf; Lq = 20; Lsrc = 64; q = bx - 60; rowbase = 15360;
  }
  const int prow = (p * 128 + b) * Lq + q;
  const int row = rowbase + prow;
  const int src = sel[prow];
  const uint4* sq = (const uint4*)(knp + ((size_t)b * Lsrc + src) * 768);
  uint4* dq = (uint4*)(qn + (size_t)row * 768);
  for (int c = threadIdx.x; c < 96; c += 128) dq[c] = sq[c];
  const float4* sx = (const float4*)(feats + ((size_t)b * Lsrc + src) * 768);
  float4* dx = (float4*)(xs + (size_t)row * 768);
  for (int c = threadIdx.x; c < 192; c += 128) dx[c] = sx[c];
}

enum { EPI_PLAIN = 0, EPI_QSCALE = 1, EPI_GELU = 2, EPI_RES_FADD = 3, EPI_RES_OUT = 4 };

template <int EPI>
__device__ __forceinline__ void epi_write(float v, size_t off, void* outp, const float* res) {
  if constexpr (EPI == EPI_QSCALE) {
    ((u16*)outp)[off] = f2b(v * 0.125f);
  } else if constexpr (EPI == EPI_GELU) {
    ((u16*)outp)[off] = f2b(gelu_fast(v));
  } else if constexpr (EPI == EPI_RES_FADD || EPI == EPI_RES_OUT) {
    ((float*)outp)[off] = v + res[off];
  } else {
    ((u16*)outp)[off] = f2b(v);
  }
}

// ---------------- GEMM 128^2, BK=32, 2-phase dbuf, 32KB LDS; bounds(256,4) [session best] ----------------
// Residency bound by the unified VGPR+AGPR file (~124/wave) -> 4 waves/SIMD max; (256,5) spills (R12).
template <int EPI>
__global__ __launch_bounds__(256, 4) void gemm_bt(const u16* __restrict__ A, const u16* __restrict__ Bt,
                                                  const float* __restrict__ bias, const float* __restrict__ res,
                                                  void* __restrict__ outp, int M, int N, int K) {
  __shared__ alignas(16) u16 As[2][4096];
  __shared__ alignas(16) u16 Bs[2][4096];
  const int tid = threadIdx.x, l = tid & 63, w = tid >> 6;
  const int nwg = gridDim.x * gridDim.y;
  int lin = blockIdx.y * gridDim.x + blockIdx.x;
  const int q8 = nwg >> 3, r8 = nwg & 7;
  const int xcd = lin & 7, pos = lin >> 3;
  const int nl = (xcd < r8) ? (xcd * (q8 + 1) + pos) : (r8 * (q8 + 1) + (xcd - r8) * q8 + pos);
  const int m0 = (nl / gridDim.x) * 128, n0 = (nl % gridDim.x) * 128;
  const int wm = (w & 1) * 64, wn = (w >> 1) * 64;
  f32x4 acc[4][4] = {};

  int arow_g[2], ach_g[2];
#pragma unroll
  for (int p = 0; p < 2; ++p) {
    const int s = p * 256 + tid;
    const int rl = s >> 3, v = (s & 7) ^ (rl & 7);
    arow_g[p] = (v >> 2) * 64 + rl;
    ach_g[p] = (v & 3) * 8;
  }
  auto STAGE = [&](int buf, int k0) {
#pragma unroll
    for (int p = 0; p < 2; ++p) {
      const int s = p * 256 + tid;
      gload16(A + (size_t)(m0 + arow_g[p]) * K + k0 + ach_g[p], &As[buf][s * 8]);
      gload16(Bt + (size_t)(n0 + arow_g[p]) * K + k0 + ach_g[p], &Bs[buf][s * 8]);
    }
  };  // 4 VMEM / thread / tile

  const int c = l >> 4;
  auto COMPUTE = [&](int buf) {
    bf16x8 af[4], bfr[4];
#pragma unroll
    for (int i = 0; i < 4; ++i) {
      const int arow = wm + i * 16 + (l & 15);
      const int slot = (c | ((arow >> 6) << 2)) ^ (arow & 7);
      af[i] = *(const bf16x8*)&As[buf][(arow & 63) * 64 + slot * 8];
      const int brow = wn + i * 16 + (l & 15);
      const int slotb = (c | ((brow >> 6) << 2)) ^ (brow & 7);
      bfr[i] = *(const bf16x8*)&Bs[buf][(brow & 63) * 64 + slotb * 8];
    }
    __builtin_amdgcn_s_setprio(1);
#pragma unroll
    for (int mi = 0; mi < 4; ++mi)
#pragma unroll
      for (int ni = 0; ni < 4; ++ni) acc[mi][ni] = mfma16(af[mi], bfr[ni], acc[mi][ni]);
    __builtin_amdgcn_s_setprio(0);
  };

  const int NT = K >> 5;
  STAGE(0, 0);
  int cur = 0;
  for (int t = 0; t < NT - 1; ++t) {
    STAGE(cur ^ 1, (t + 1) << 5);
    asm volatile("s_waitcnt vmcnt(4)" ::: "memory");
    __builtin_amdgcn_sched_barrier(0);
    __builtin_amdgcn_s_barrier();
    COMPUTE(cur);
    __builtin_amdgcn_s_barrier();
    cur ^= 1;
  }
  asm volatile("s_waitcnt vmcnt(0)" ::: "memory");
  __builtin_amdgcn_sched_barrier(0);
  __builtin_amdgcn_s_barrier();
  COMPUTE(cur);

  const int r4 = (l >> 4) * 4, c16 = l & 15;
#pragma unroll
  for (int mi = 0; mi < 4; ++mi)
#pragma unroll
    for (int ni = 0; ni < 4; ++ni) {
      const int gn = n0 + wn + ni * 16 + c16;
      const float bia = bias[gn];
#pragma unroll
      for (int j = 0; j < 4; ++j) {
        const int gm = m0 + wm + mi * 16 + r4 + j;
        epi_write<EPI>(acc[mi][ni][j] + bia, (size_t)gm * N + gn, outp, res);
      }
    }
}

// ---------------- attention: one WG per (head, part*batch); K/V interleaved [row][1536] ----------------
template <int LQP, int LKP, int LQ, int LK, bool MASK>
__global__ __launch_bounds__(256) void attn2(const u16* __restrict__ Q, const u16* __restrict__ KVb,
                                             const int* __restrict__ toks, u16* __restrict__ O) {
  constexpr int LKS = LKP + 8;
  const int h = blockIdx.x, by = blockIdx.y;
  const int p = by & 1, bb = by >> 1;
  const int tid = threadIdx.x, l = tid & 63, w = tid >> 6;
  const size_t qrow0 = (size_t)(p * 128 + bb) * LQ;
  const u16* Qg = Q + qrow0 * 768 + h * 64;
  const u16* Kg = KVb + (size_t)bb * LK * 1536 + h * 64;
  const u16* Vg = Kg + 768;

  __shared__ alignas(16) u16 Qs[LQP * 64];
  __shared__ alignas(16) u16 KV[64 * LKS];
  __shared__ alignas(16) u16 Ss[LQP * LKS];
  __shared__ int tokLds[MASK ? LKP : 1];

  for (int s = tid; s < LQP * 8; s += 256) {
    int row = s >> 3, d8 = (s & 7) ^ (row & 7);
    int gr = row < LQ ? row : LQ - 1;
    gload16(Qg + (size_t)gr * 768 + d8 * 8, &Qs[s * 8]);
  }
  for (int s = tid; s < LKP * 8; s += 256) {
    int row = s >> 3, d8 = (s & 7) ^ (row & 7);
    int gr = row < LK ? row : LK - 1;
    gload16(Kg + (size_t)gr * 1536 + d8 * 8, &KV[s * 8]);
  }
  if (MASK)
    for (int c = tid; c < LKP; c += 256) tokLds[c] = (c < LK) ? toks[bb * LK + c] : 1;
  __syncthreads();

  for (int nt = w; nt < LKP / 16; nt += 4) {
    const int brow = nt * 16 + (l & 15);
#pragma unroll
    for (int mt = 0; mt < LQP / 16; ++mt) {
      const int arow = mt * 16 + (l & 15);
      f32x4 a_ = {0.f, 0.f, 0.f, 0.f};
#pragma unroll
      for (int kk = 0; kk < 2; ++kk) {
        bf16x8 av = *(const bf16x8*)&Qs[arow * 64 + (((kk * 4 + (l >> 4)) ^ (arow & 7)) << 3)];
        bf16x8 bv = *(const bf16x8*)&KV[brow * 64 + (((kk * 4 + (l >> 4)) ^ (brow & 7)) << 3)];
        a_ = mfma16(av, bv, a_);
      }
      const int r0 = mt * 16 + (l >> 4) * 4, cc = nt * 16 + (l & 15);
#pragma unroll
      for (int j = 0; j < 4; ++j) Ss[(r0 + j) * LKS + cc] = f2b(a_[j]);
    }
  }
  __syncthreads();

  {
    const int kcol = tid & 31, d8 = tid >> 5;
#pragma unroll
    for (int kb = 0; kb < LKP / 32; ++kb) {
      const int k = kb * 32 + kcol;
      alignas(16) u16 tmp[8] = {0, 0, 0, 0, 0, 0, 0, 0};
      if (k < LK) *(uint4*)tmp = *(const uint4*)(Vg + (size_t)k * 1536 + d8 * 8);
#pragma unroll
      for (int j = 0; j < 8; ++j) KV[(d8 * 8 + j) * LKS + k] = tmp[j];
    }
  }
  constexpr int NCH = (LKP + 63) / 64;
  for (int r = w; r < LQ; r += 4) {
    float sv[NCH];
    float mx = -INFINITY;
#pragma unroll
    for (int i = 0; i < NCH; ++i) {
      int c = l + (i << 6);
      float s = -INFINITY;
      if (c < LK) {
        s = b2f(Ss[r * LKS + c]);
        if (MASK && tokLds[c] == 0) s = -1e9f;
      }
      sv[i] = s;
      mx = fmaxf(mx, s);
    }
    for (int d = 1; d < 64; d <<= 1) mx = fmaxf(mx, __shfl_xor(mx, d));
    float sum = 0.f;
#pragma unroll
    for (int i = 0; i < NCH; ++i) { float e = __expf(sv[i] - mx); sv[i] = e; sum += e; }
    for (int d = 1; d < 64; d <<= 1) sum += __shfl_xor(sum, d);
    const float inv = 1.0f / sum;
#pragma unroll
    for (int i = 0; i < NCH; ++i) {
      int c = l + (i << 6);
      if (c < LKP) Ss[r * LKS + c] = f2b(sv[i] * inv);
    }
  }
  __syncthreads();

  for (int mt = w; mt < LQP / 16; mt += 4) {
    const int arow = mt * 16 + (l & 15);
#pragma unroll
    for (int nt = 0; nt < 4; ++nt) {
      f32x4 a_ = {0.f, 0.f, 0.f, 0.f};
#pragma unroll
      for (int kk = 0; kk < LKP; kk += 32) {
        bf16x8 av = *(const bf16x8*)&Ss[arow * LKS + kk + (l >> 4) * 8];
        bf16x8 bv = *(const bf16x8*)&KV[(nt * 16 + (l & 15)) * LKS + kk + (l >> 4) * 8];
        a_ = mfma16(av, bv, a_);
      }
      const int r0 = mt * 16 + (l >> 4) * 4, c16 = l & 15;
#pragma unroll
      for (int j = 0; j < 4; ++j) {
        int r = r0 + j;
        if (r < LQ) O[(qrow0 + r) * 768 + h * 64 + nt * 16 + c16] = f2b(a_[j]);
      }
    }
  }
}

// ---------------------------------------------------------------
extern "C" void kernel_launch(void* const* d_in, const int* in_sizes, int n_in,
                              void* d_out, int out_size, void* d_ws, size_t ws_size,
                              hipStream_t stream) {
  (void)in_sizes; (void)n_in; (void)out_size; (void)ws_size;
  const float* image_feats = (const float*)d_in[0];
  const float* image_att = (const float*)d_in[1];
  const float* text_feats = (const float*)d_in[2];
  const float* text_att = (const float*)d_in[3];
  const int* tokens = (const int*)d_in[4];
  const float* bn_img_g = (const float*)d_in[5];
  const float* bn_img_b = (const float*)d_in[6];
  const float* bn_img_m = (const float*)d_in[7];
  const float* bn_img_v = (const float*)d_in[8];
  const float* bn_txt_g = (const float*)d_in[9];
  const float* bn_txt_b = (const float*)d_in[10];
  const float* bn_txt_m = (const float*)d_in[11];
  const float* bn_txt_v = (const float*)d_in[12];
  const float* ln1_g = (const float*)d_in[13];
  const float* ln1_b = (const float*)d_in[14];
  const float* ln2_g = (const float*)d_in[15];
  const float* ln2_b = (const float*)d_in[16];
  const float* Wq = (const float*)d_in[17];
  const float* Wk = (const float*)d_in[18];
  const float* Wv = (const float*)d_in[19];
  const float* Wo = (const float*)d_in[20];
  const float* bq = (const float*)d_in[21];
  const float* bk = (const float*)d_in[22];
  const float* bv = (const float*)d_in[23];
  const float* bo = (const float*)d_in[24];
  const float* W1 = (const float*)d_in[25];
  const float* b1 = (const float*)d_in[26];
  const float* W2 = (const float*)d_in[27];
  const float* b2 = (const float*)d_in[28];

  float* out = (float*)d_out;
  char* wsp = (char*)d_ws;
  size_t off = 0;
  auto alloc = [&](size_t bytes) -> void* {
    void* p = wsp + off;
    off += (bytes + 255) & ~(size_t)255;
    return p;
  };
  // weights
  u16* WqT = (u16*)alloc(768 * 768 * 2);
  u16* WkvT = (u16*)alloc((size_t)1536 * 768 * 2);  // rows 0-767 = Wk^T, 768-1535 = Wv^T
  u16* WoT = (u16*)alloc(768 * 768 * 2);
  u16* W1T = (u16*)alloc((size_t)768 * 3072 * 2);
  u16* W2T = (u16*)alloc((size_t)768 * 3072 * 2);
  float* bkv = (float*)alloc(1536 * 4);
  // combined K/V row space: rows 0..25215 image, 25216..33407 text (33408 = 261*128)
  char* kvbase = (char*)(wsp + off);
  u16* kn = (u16*)alloc((size_t)33408 * 768 * 2);
  u16* KVb = (u16*)alloc((size_t)33408 * 1536 * 2);  // [row][0:768]=K, [768:1536]=V
  u16* KVb_t = KVb + (size_t)25216 * 1536;
  u16* gb = (u16*)kvbase;  // FF intermediate [20480 x 3072] bf16 = 126MB (aliases dead K/V region)
  int* sel_i = (int*)alloc(2 * 128 * 60 * 4);
  int* sel_t = (int*)alloc(2 * 128 * 20 * 4);
  u16* qn = (u16*)alloc((size_t)20480 * 768 * 2);
  float* xs = (float*)alloc((size_t)20480 * 768 * 4);
  u16* Qb = (u16*)alloc((size_t)20480 * 768 * 2);

  const dim3 tb(32, 8);
  transpose_all<<<6913, tb, 0, stream>>>(Wq, Wk, Wv, Wo, W1, W2, bk, bv, WqT, WkvT, WoT, W1T, W2T, bkv);

  bn_both<<<dim3(128, 2), 256, 0, stream>>>(image_feats, text_feats, bn_img_g, bn_img_b, bn_img_m, bn_img_v,
                                            bn_txt_g, bn_txt_b, bn_txt_m, bn_txt_v, out);
  topk_both<<<dim3(128, 2), 256, 0, stream>>>(image_att, text_att, sel_i, sel_t);

  // LN1 of both modalities into combined kn, then ONE fused K+V projection (M=33408, N=1536)
  ln1_both<<<33408 / 4, 256, 0, stream>>>(image_feats, text_feats, ln1_g, ln1_b, kn);
  gemm_bt<EPI_PLAIN><<<dim3(12, 261), 256, 0, stream>>>(kn, WkvT, bkv, nullptr, KVb, 33408, 1536, 768);

  // both gathers in one launch
  gather_both<<<dim3(80, 256), 128, 0, stream>>>(sel_i, sel_t, kn, image_feats, text_feats, qn, xs);

  // Q projection (combined, pre-scaled by 1/sqrt(64))
  gemm_bt<EPI_QSCALE><<<dim3(6, 160), 256, 0, stream>>>(qn, WqT, bq, nullptr, Qb, 20480, 768, 768);

  // attention (writes att-out into qn)
  attn2<64, 224, 60, 197, false><<<dim3(12, 256), 256, 0, stream>>>(Qb, KVb, nullptr, qn);
  attn2<32, 64, 20, 64, true><<<dim3(12, 256), 256, 0, stream>>>(Qb + (size_t)15360 * 768, KVb_t,
                                                                 tokens, qn + (size_t)15360 * 768);

  // x1 = xs + att@Wo + bo   (in-place on xs)
  gemm_bt<EPI_RES_FADD><<<dim3(6, 160), 256, 0, stream>>>(qn, WoT, bo, xs, xs, 20480, 768, 768);
  // h = LN2(x1)
  ln_rows<<<20480 / 4, 256, 0, stream>>>(xs, ln2_g, ln2_b, Qb);
  // gb = gelu(h@W1 + b1)
  gemm_bt<EPI_GELU><<<dim3(24, 160), 256, 0, stream>>>(Qb, W1T, b1, nullptr, gb, 20480, 3072, 768);
  // out = x1 + gb@W2 + b2
  gemm_bt<EPI_RES_OUT><<<dim3(6, 160), 256, 0, stream>>>(gb, W2T, b2, xs, out + 196608, 20480, 768, 3072);
}